// Round 1
// baseline (364.116 us; speedup 1.0000x reference)
//
#include <hip/hip_runtime.h>
#include <hip/hip_bf16.h>
#include <math.h>

#define B_ 8
#define S_ 1024
#define E_ 768
#define H_ 12
#define P_ 64

typedef __attribute__((ext_vector_type(8))) short bf16x8;
typedef __attribute__((ext_vector_type(4))) float f32x4;

__device__ __forceinline__ short f2bf(float f) {
    union { float f; unsigned u; } v; v.f = f;
    unsigned r = v.u + 0x7FFFu + ((v.u >> 16) & 1u);  // round-to-nearest-even
    return (short)(r >> 16);
}

// HW bf16 convert (RNE on gfx950; compiler emits v_cvt_pk_bf16_f32 — m240:
// the scalar-cast path beats hand-written asm).
__device__ __forceinline__ short f2bf_hw(float f) {
    union { __hip_bfloat16 h; short s; } cv;
    cv.h = __float2bfloat16(f);
    return cv.s;
}

// ---------------------------------------------------------------------------
// fp32 -> bf16 straight conversion (n multiple of 1024)
// ---------------------------------------------------------------------------
__global__ __launch_bounds__(256) void conv_bf16_kernel(
    const float4* __restrict__ src, ushort4* __restrict__ dst)
{
    int idx = blockIdx.x * 256 + threadIdx.x;
    float4 f = src[idx];
    ushort4 u;
    u.x = (unsigned short)f2bf(f.x);
    u.y = (unsigned short)f2bf(f.y);
    u.z = (unsigned short)f2bf(f.z);
    u.w = (unsigned short)f2bf(f.w);
    dst[idx] = u;
}

// ---------------------------------------------------------------------------
// fp32 [batch][R][C] -> bf16 [batch][C][R] transpose. grid (R/64, C/64, batch)
// ---------------------------------------------------------------------------
__global__ __launch_bounds__(256) void conv_T_kernel(
    const float* __restrict__ src0, short* __restrict__ dst0, int R, int C)
{
    __shared__ short T[64][72];
    const int t = threadIdx.x;
    const int r0 = blockIdx.x * 64, c0 = blockIdx.y * 64;
    const size_t bo = (size_t)blockIdx.z * R * C;
    const float* src = src0 + bo;
    short* dst = dst0 + bo;
#pragma unroll
    for (int i = 0; i < 4; ++i) {
        int id = i * 256 + t;
        int r = id >> 4, c4 = id & 15;
        float4 f = *(const float4*)(src + (size_t)(r0 + r) * C + c0 + c4 * 4);
        T[c4 * 4 + 0][r] = f2bf(f.x);
        T[c4 * 4 + 1][r] = f2bf(f.y);
        T[c4 * 4 + 2][r] = f2bf(f.z);
        T[c4 * 4 + 3][r] = f2bf(f.w);
    }
    __syncthreads();
#pragma unroll
    for (int i = 0; i < 2; ++i) {
        int id = i * 256 + t;
        int cc = id >> 3, r8 = id & 7;
        *(uint4*)(dst + (size_t)(c0 + cc) * R + r0 + r8 * 8) = *(const uint4*)&T[cc][r8 * 8];
    }
}

// ---------------------------------------------------------------------------
// MFMA GEMM core: C(128x64) = A(128xK) @ Bt(64xK)^T.  (unchanged)
// ---------------------------------------------------------------------------
__device__ __forceinline__ void mfma_gemm_128x64(
    const short* __restrict__ A, int lda,
    const short* __restrict__ Bt, int ldb, int K,
    short (*As)[72], short (*Bs)[72], f32x4 (&acc)[2][4])
{
    const int tid = threadIdx.x;
    const int w = tid >> 6, lane = tid & 63, quad = lane >> 4, ln = lane & 15;

    for (int k0 = 0; k0 < K; k0 += 64) {
        __syncthreads();
#pragma unroll
        for (int i = 0; i < 4; ++i) {           // A tile: 128 rows x 8 chunks
            int id = i * 256 + tid;
            int r = id >> 3, c8 = id & 7;
            *(uint4*)&As[r][c8 * 8] = *(const uint4*)(A + (size_t)r * lda + k0 + c8 * 8);
        }
#pragma unroll
        for (int i = 0; i < 2; ++i) {           // Bt tile: 64 rows x 8 chunks
            int id = i * 256 + tid;
            int r = id >> 3, c8 = id & 7;
            *(uint4*)&Bs[r][c8 * 8] = *(const uint4*)(Bt + (size_t)r * ldb + k0 + c8 * 8);
        }
        __syncthreads();
#pragma unroll
        for (int kc = 0; kc < 2; ++kc) {
            bf16x8 a0 = *(const bf16x8*)&As[w * 32 + ln][kc * 32 + quad * 8];
            bf16x8 a1 = *(const bf16x8*)&As[w * 32 + 16 + ln][kc * 32 + quad * 8];
#pragma unroll
            for (int ni = 0; ni < 4; ++ni) {
                bf16x8 b = *(const bf16x8*)&Bs[ni * 16 + ln][kc * 32 + quad * 8];
                acc[0][ni] = __builtin_amdgcn_mfma_f32_16x16x32_bf16(a0, b, acc[0][ni], 0, 0, 0);
                acc[1][ni] = __builtin_amdgcn_mfma_f32_16x16x32_bf16(a1, b, acc[1][ni], 0, 0, 0);
            }
        }
    }
}

// ---------------------------------------------------------------------------
// Stage 1: k = x @ key_proj (z=0), v = x @ value_proj (z=1, transposed out).
// ---------------------------------------------------------------------------
__global__ __launch_bounds__(256) void proj_kv_mfma(
    const short* __restrict__ xb,
    const short* __restrict__ kTw,   // [h][p][e] bf16
    const short* __restrict__ vTw,
    short* __restrict__ kb,          // [b][h][s][p]
    short* __restrict__ vTb)         // [b][h][p][s]
{
    __shared__ short As[128][72];
    __shared__ short Bs[64][72];
    const int tid = threadIdx.x;
    const int w = tid >> 6, lane = tid & 63, quad = lane >> 4, ln = lane & 15;
    const int m0 = blockIdx.x * 128;
    const int h = blockIdx.y, z = blockIdx.z;

    const short* Bt = (z ? vTw : kTw) + (size_t)h * P_ * E_;
    f32x4 acc[2][4] = {};
    mfma_gemm_128x64(xb + (size_t)m0 * E_, E_, Bt, E_, E_, As, Bs, acc);

    const int b = m0 >> 10;
    const int sbase = (m0 & 1023) + w * 32;
    if (z == 0) {
        short* outp = kb + ((size_t)(b * H_ + h)) * S_ * P_;
#pragma unroll
        for (int mi = 0; mi < 2; ++mi)
#pragma unroll
            for (int ni = 0; ni < 4; ++ni)
#pragma unroll
                for (int r = 0; r < 4; ++r) {
                    int s = sbase + mi * 16 + quad * 4 + r;
                    outp[(size_t)s * P_ + ni * 16 + ln] = f2bf(acc[mi][ni][r]);
                }
    } else {
        short* outp = vTb + ((size_t)(b * H_ + h)) * P_ * S_;
#pragma unroll
        for (int mi = 0; mi < 2; ++mi)
#pragma unroll
            for (int ni = 0; ni < 4; ++ni) {
                int p = ni * 16 + ln;
                int s = sbase + mi * 16 + quad * 4;  // 4 consecutive s in regs
                ushort4 u;
                u.x = (unsigned short)f2bf(acc[mi][ni][0]);
                u.y = (unsigned short)f2bf(acc[mi][ni][1]);
                u.z = (unsigned short)f2bf(acc[mi][ni][2]);
                u.w = (unsigned short)f2bf(acc[mi][ni][3]);
                *(ushort4*)(outp + (size_t)p * S_ + s) = u;
            }
    }
}

// ---------------------------------------------------------------------------
// Stage 2: qv[b,h] = q_heads[h] @ v[b,h]; B-operand is vT (already Bt form).
// ---------------------------------------------------------------------------
__global__ __launch_bounds__(256) void qv_mfma(
    const short* __restrict__ qhb,
    const short* __restrict__ vTb,
    short* __restrict__ qvb)
{
    __shared__ short As[128][72];
    __shared__ short Bs[64][72];
    const int tid = threadIdx.x;
    const int w = tid >> 6, lane = tid & 63, quad = lane >> 4, ln = lane & 15;
    const int m0 = blockIdx.x * 128;
    const int bh = blockIdx.y;
    const int h = bh % H_;

    f32x4 acc[2][4] = {};
    mfma_gemm_128x64(qhb + (size_t)h * S_ * S_ + (size_t)m0 * S_, S_,
                     vTb + (size_t)bh * P_ * S_, S_, S_, As, Bs, acc);

    short* outp = qvb + (size_t)bh * S_ * P_;
#pragma unroll
    for (int mi = 0; mi < 2; ++mi)
#pragma unroll
        for (int ni = 0; ni < 4; ++ni)
#pragma unroll
            for (int r = 0; r < 4; ++r) {
                int s = m0 + w * 32 + mi * 16 + quad * 4 + r;
                outp[(size_t)s * P_ + ni * 16 + ln] = f2bf(acc[mi][ni][r]);
            }
}

// ---------------------------------------------------------------------------
// Stage 3: barrier-free flash attention.
//
// Rationale (rocprof: MfmaUtil 5%, VALUBusy 25%, occ 15% -> latency-bound):
//  - K/V MFMA B-fragments are read DIRECTLY from global (L2-resident 256KB
//    per bh; 16B/lane, 64B-contiguous per quad group = fully coalesced).
//    No K/V LDS staging -> no __syncthreads at all.
//  - No-max softmax: setup scales weights by 0.02, |logit| <= ~0.45 even at
//    5-sigma, so p = exp2(c2*s) directly (exact same real-arithmetic result
//    as softmax->tril->renorm). Masked cols zeroed AFTER exp. Row-sum l is
//    accumulated per-lane and reduced ONCE in the epilogue -> the 8-deep
//    per-tile shfl chain and the alpha-rescale of o are gone.
//  - 2 waves/block, 32 q-rows/wave (2 strips share each loaded K/V fragment
//    -> halves L2 traffic per unit work). LDS = wave-private P relayout only
//    (9.2KB/block). Same-wave DS ops are in-order -> no barrier needed.
// ---------------------------------------------------------------------------
template<bool DIAG>
__device__ __forceinline__ void flash_tile(
    const short* __restrict__ Kj,   // K tile base: rows [0,64) x P_
    const short* __restrict__ Vj,   // Vt + jt*64 (row stride S_)
    const bf16x8 (&qf)[2][2], short (*Pw)[72],
    f32x4 (&o)[2][4], float (&l)[2][4],
    int w, int quad, int ln)
{
    const float c2 = 0.03608439182435161f * 1.4426950408889634f; // scale*log2(e)

    // S strips (2 x 16x64) = Q strips @ K^T ; kf straight from global (L2)
    f32x4 s[2][4] = {};
#pragma unroll
    for (int kc = 0; kc < 2; ++kc)
#pragma unroll
        for (int ni = 0; ni < 4; ++ni) {
            bf16x8 kf = *(const bf16x8*)(Kj + (size_t)(ni * 16 + ln) * P_ + kc * 32 + quad * 8);
            s[0][ni] = __builtin_amdgcn_mfma_f32_16x16x32_bf16(qf[0][kc], kf, s[0][ni], 0, 0, 0);
            s[1][ni] = __builtin_amdgcn_mfma_f32_16x16x32_bf16(qf[1][kc], kf, s[1][ni], 0, 0, 0);
        }

    // p = exp2(c2*s) (no max-subtract); zero masked AFTER exp; defer l-reduce
#pragma unroll
    for (int u = 0; u < 2; ++u)
#pragma unroll
        for (int r = 0; r < 4; ++r) {
            const int row = u * 16 + quad * 4 + r;   // row within q-block half
            float p[4];
#pragma unroll
            for (int ni = 0; ni < 4; ++ni) {
                float v = __builtin_amdgcn_exp2f(c2 * s[u][ni][r]);
                if (DIAG && (ni * 16 + ln) > (w * 32 + row)) v = 0.f;
                p[ni] = v;
                l[u][r] += v;
            }
#pragma unroll
            for (int ni = 0; ni < 4; ++ni)
                Pw[row][ni * 16 + ln] = f2bf_hw(p[ni]);
        }

    // O strips += P @ V ; P via wave-private LDS (same-wave DS is in-order),
    // vb straight from global (L2)
#pragma unroll
    for (int kc = 0; kc < 2; ++kc) {
        bf16x8 pa0 = *(const bf16x8*)&Pw[ln][kc * 32 + quad * 8];
        bf16x8 pa1 = *(const bf16x8*)&Pw[16 + ln][kc * 32 + quad * 8];
#pragma unroll
        for (int ni = 0; ni < 4; ++ni) {
            bf16x8 vb = *(const bf16x8*)(Vj + (size_t)(ni * 16 + ln) * S_ + kc * 32 + quad * 8);
            o[0][ni] = __builtin_amdgcn_mfma_f32_16x16x32_bf16(pa0, vb, o[0][ni], 0, 0, 0);
            o[1][ni] = __builtin_amdgcn_mfma_f32_16x16x32_bf16(pa1, vb, o[1][ni], 0, 0, 0);
        }
    }
}

__global__ __launch_bounds__(128) void flash_mfma(
    const short* __restrict__ kb,
    const short* __restrict__ qvb,
    const short* __restrict__ vTb,
    short* __restrict__ attn2)
{
    __shared__ short Ps[2][32][72];   // per-wave P relayout region

    const int tid = threadIdx.x;
    const int w = tid >> 6, lane = tid & 63, quad = lane >> 4, ln = lane & 15;
    const int qb = (int)(gridDim.x - 1 - blockIdx.x);   // long blocks first
    const int bh = blockIdx.y;
    const int b = bh / H_, h = bh % H_;

    const short* Q  = kb  + (size_t)bh * S_ * P_ + ((size_t)qb * 64 + w * 32) * P_;
    const short* K  = qvb + (size_t)bh * S_ * P_;
    const short* Vt = vTb + (size_t)bh * P_ * S_;

    // Q fragments direct from global (one-time, coalesced)
    bf16x8 qf[2][2];
#pragma unroll
    for (int u = 0; u < 2; ++u)
#pragma unroll
        for (int kc = 0; kc < 2; ++kc)
            qf[u][kc] = *(const bf16x8*)(Q + (size_t)(u * 16 + ln) * P_ + kc * 32 + quad * 8);

    f32x4 o[2][4] = {};
    float l[2][4] = {};
    short (*Pw)[72] = Ps[w];

    for (int jt = 0; jt < qb; ++jt)
        flash_tile<false>(K + (size_t)jt * 64 * P_, Vt + jt * 64, qf, Pw, o, l, w, quad, ln);
    flash_tile<true>(K + (size_t)qb * 64 * P_, Vt + qb * 64, qf, Pw, o, l, w, quad, ln);

    // epilogue: one row-sum reduce per row, then scale + store bf16
#pragma unroll
    for (int u = 0; u < 2; ++u)
#pragma unroll
        for (int r = 0; r < 4; ++r) {
            float lv = l[u][r];
#pragma unroll
            for (int off = 1; off < 16; off <<= 1)
                lv += __shfl_xor(lv, off, 16);
            float inv = 1.0f / lv;
            int gi = qb * 64 + w * 32 + u * 16 + quad * 4 + r;
#pragma unroll
            for (int ni = 0; ni < 4; ++ni)
                attn2[((size_t)b * S_ + gi) * (H_ * P_) + h * P_ + ni * 16 + ln] =
                    f2bf(o[u][ni][r] * inv);
        }
}

// ---------------------------------------------------------------------------
// Stage 4: out(8192x768) = attn2 @ lifting, via liftT (Bt form). grid (64,12).
// ---------------------------------------------------------------------------
__global__ __launch_bounds__(256) void lift_mfma(
    const short* __restrict__ attn2,
    const short* __restrict__ liftT,
    float* __restrict__ outp)
{
    __shared__ short As[128][72];
    __shared__ short Bs[64][72];
    const int tid = threadIdx.x;
    const int w = tid >> 6, lane = tid & 63, quad = lane >> 4, ln = lane & 15;
    const int m0 = blockIdx.x * 128;
    const int n0 = blockIdx.y * 64;

    f32x4 acc[2][4] = {};
    mfma_gemm_128x64(attn2 + (size_t)m0 * E_, E_,
                     liftT + (size_t)n0 * E_, E_, E_, As, Bs, acc);

#pragma unroll
    for (int mi = 0; mi < 2; ++mi)
#pragma unroll
        for (int ni = 0; ni < 4; ++ni)
#pragma unroll
            for (int r = 0; r < 4; ++r) {
                int m = m0 + w * 32 + mi * 16 + quad * 4 + r;
                outp[(size_t)m * E_ + n0 + ni * 16 + ln] = acc[mi][ni][r];
            }
}

extern "C" void kernel_launch(void* const* d_in, const int* in_sizes, int n_in,
                              void* d_out, int out_size, void* d_ws, size_t ws_size,
                              hipStream_t stream) {
    (void)in_sizes; (void)n_in; (void)out_size; (void)ws_size;
    const float* x       = (const float*)d_in[0];
    const float* kproj   = (const float*)d_in[1];
    const float* vproj   = (const float*)d_in[2];
    const float* qheads  = (const float*)d_in[3];
    const float* lifting = (const float*)d_in[4];
    float* out = (float*)d_out;

    short* ws = (short*)d_ws;
    const size_t N_X   = (size_t)B_ * S_ * E_;          // 6,291,456
    const size_t N_QH  = (size_t)H_ * S_ * S_;          // 12,582,912
    const size_t N_W   = (size_t)H_ * P_ * E_;          //    589,824
    const size_t N_L   = (size_t)E_ * E_;               //    589,824
    const size_t N_KV  = (size_t)B_ * H_ * S_ * P_;     // 6,291,456

    short* xb    = ws;                 ws += N_X;
    short* qhb   = ws;                 ws += N_QH;
    short* kTw   = ws;                 ws += N_W;
    short* vTw   = ws;                 ws += N_W;
    short* liftT = ws;                 ws += N_L;
    short* kb    = ws;                 ws += N_KV;
    short* vTb   = ws;                 ws += N_KV;
    short* qvb   = ws;                 ws += N_KV;
    short* attn2 = ws;                 ws += N_KV;

    conv_bf16_kernel<<<(int)(N_X / 1024), 256, 0, stream>>>((const float4*)x, (ushort4*)xb);
    conv_bf16_kernel<<<(int)(N_QH / 1024), 256, 0, stream>>>((const float4*)qheads, (ushort4*)qhb);
    conv_T_kernel<<<dim3(E_ / 64, P_ / 64, H_), 256, 0, stream>>>(kproj, kTw, E_, P_);
    conv_T_kernel<<<dim3(E_ / 64, P_ / 64, H_), 256, 0, stream>>>(vproj, vTw, E_, P_);
    conv_T_kernel<<<dim3(E_ / 64, E_ / 64, 1), 256, 0, stream>>>(lifting, liftT, E_, E_);

    proj_kv_mfma<<<dim3((B_ * S_) / 128, H_, 2), 256, 0, stream>>>(xb, kTw, vTw, kb, vTb);
    qv_mfma<<<dim3(S_ / 128, B_ * H_), 256, 0, stream>>>(qhb, vTb, qvb);
    flash_mfma<<<dim3(S_ / 64, B_ * H_), 128, 0, stream>>>(kb, qvb, vTb, attn2);
    lift_mfma<<<dim3((B_ * S_) / 128, E_ / 64), 256, 0, stream>>>(attn2, liftT, out);
}

// Round 2
// 341.701 us; speedup vs baseline: 1.0656x; 1.0656x over previous
//
#include <hip/hip_runtime.h>
#include <hip/hip_bf16.h>
#include <math.h>

#define B_ 8
#define S_ 1024
#define E_ 768
#define H_ 12
#define P_ 64

typedef __attribute__((ext_vector_type(8))) short bf16x8;
typedef __attribute__((ext_vector_type(4))) float f32x4;

__device__ __forceinline__ short f2bf(float f) {
    union { float f; unsigned u; } v; v.f = f;
    unsigned r = v.u + 0x7FFFu + ((v.u >> 16) & 1u);  // round-to-nearest-even
    return (short)(r >> 16);
}

// HW bf16 convert (compiler emits v_cvt path; m240: beats hand asm).
__device__ __forceinline__ short f2bf_hw(float f) {
    union { __hip_bfloat16 h; short s; } cv;
    cv.h = __float2bfloat16(f);
    return cv.s;
}

// ---------------------------------------------------------------------------
// fp32 -> bf16 straight conversion (n multiple of 1024)
// ---------------------------------------------------------------------------
__global__ __launch_bounds__(256) void conv_bf16_kernel(
    const float4* __restrict__ src, ushort4* __restrict__ dst)
{
    int idx = blockIdx.x * 256 + threadIdx.x;
    float4 f = src[idx];
    ushort4 u;
    u.x = (unsigned short)f2bf(f.x);
    u.y = (unsigned short)f2bf(f.y);
    u.z = (unsigned short)f2bf(f.z);
    u.w = (unsigned short)f2bf(f.w);
    dst[idx] = u;
}

// ---------------------------------------------------------------------------
// fp32 [batch][R][C] -> bf16 [batch][C][R] transpose. grid (R/64, C/64, batch)
// ---------------------------------------------------------------------------
__global__ __launch_bounds__(256) void conv_T_kernel(
    const float* __restrict__ src0, short* __restrict__ dst0, int R, int C)
{
    __shared__ short T[64][72];
    const int t = threadIdx.x;
    const int r0 = blockIdx.x * 64, c0 = blockIdx.y * 64;
    const size_t bo = (size_t)blockIdx.z * R * C;
    const float* src = src0 + bo;
    short* dst = dst0 + bo;
#pragma unroll
    for (int i = 0; i < 4; ++i) {
        int id = i * 256 + t;
        int r = id >> 4, c4 = id & 15;
        float4 f = *(const float4*)(src + (size_t)(r0 + r) * C + c0 + c4 * 4);
        T[c4 * 4 + 0][r] = f2bf(f.x);
        T[c4 * 4 + 1][r] = f2bf(f.y);
        T[c4 * 4 + 2][r] = f2bf(f.z);
        T[c4 * 4 + 3][r] = f2bf(f.w);
    }
    __syncthreads();
#pragma unroll
    for (int i = 0; i < 2; ++i) {
        int id = i * 256 + t;
        int cc = id >> 3, r8 = id & 7;
        *(uint4*)(dst + (size_t)(c0 + cc) * R + r0 + r8 * 8) = *(const uint4*)&T[cc][r8 * 8];
    }
}

// ---------------------------------------------------------------------------
// MFMA GEMM core: C(128x64) = A(128xK) @ Bt(64xK)^T.  (unchanged)
// ---------------------------------------------------------------------------
__device__ __forceinline__ void mfma_gemm_128x64(
    const short* __restrict__ A, int lda,
    const short* __restrict__ Bt, int ldb, int K,
    short (*As)[72], short (*Bs)[72], f32x4 (&acc)[2][4])
{
    const int tid = threadIdx.x;
    const int w = tid >> 6, lane = tid & 63, quad = lane >> 4, ln = lane & 15;

    for (int k0 = 0; k0 < K; k0 += 64) {
        __syncthreads();
#pragma unroll
        for (int i = 0; i < 4; ++i) {           // A tile: 128 rows x 8 chunks
            int id = i * 256 + tid;
            int r = id >> 3, c8 = id & 7;
            *(uint4*)&As[r][c8 * 8] = *(const uint4*)(A + (size_t)r * lda + k0 + c8 * 8);
        }
#pragma unroll
        for (int i = 0; i < 2; ++i) {           // Bt tile: 64 rows x 8 chunks
            int id = i * 256 + tid;
            int r = id >> 3, c8 = id & 7;
            *(uint4*)&Bs[r][c8 * 8] = *(const uint4*)(Bt + (size_t)r * ldb + k0 + c8 * 8);
        }
        __syncthreads();
#pragma unroll
        for (int kc = 0; kc < 2; ++kc) {
            bf16x8 a0 = *(const bf16x8*)&As[w * 32 + ln][kc * 32 + quad * 8];
            bf16x8 a1 = *(const bf16x8*)&As[w * 32 + 16 + ln][kc * 32 + quad * 8];
#pragma unroll
            for (int ni = 0; ni < 4; ++ni) {
                bf16x8 b = *(const bf16x8*)&Bs[ni * 16 + ln][kc * 32 + quad * 8];
                acc[0][ni] = __builtin_amdgcn_mfma_f32_16x16x32_bf16(a0, b, acc[0][ni], 0, 0, 0);
                acc[1][ni] = __builtin_amdgcn_mfma_f32_16x16x32_bf16(a1, b, acc[1][ni], 0, 0, 0);
            }
        }
    }
}

// ---------------------------------------------------------------------------
// Stage 1: k = x @ key_proj (z=0), v = x @ value_proj (z=1, transposed out).
// ---------------------------------------------------------------------------
__global__ __launch_bounds__(256) void proj_kv_mfma(
    const short* __restrict__ xb,
    const short* __restrict__ kTw,   // [h][p][e] bf16
    const short* __restrict__ vTw,
    short* __restrict__ kb,          // [b][h][s][p]
    short* __restrict__ vTb)         // [b][h][p][s]
{
    __shared__ short As[128][72];
    __shared__ short Bs[64][72];
    const int tid = threadIdx.x;
    const int w = tid >> 6, lane = tid & 63, quad = lane >> 4, ln = lane & 15;
    const int m0 = blockIdx.x * 128;
    const int h = blockIdx.y, z = blockIdx.z;

    const short* Bt = (z ? vTw : kTw) + (size_t)h * P_ * E_;
    f32x4 acc[2][4] = {};
    mfma_gemm_128x64(xb + (size_t)m0 * E_, E_, Bt, E_, E_, As, Bs, acc);

    const int b = m0 >> 10;
    const int sbase = (m0 & 1023) + w * 32;
    if (z == 0) {
        short* outp = kb + ((size_t)(b * H_ + h)) * S_ * P_;
#pragma unroll
        for (int mi = 0; mi < 2; ++mi)
#pragma unroll
            for (int ni = 0; ni < 4; ++ni)
#pragma unroll
                for (int r = 0; r < 4; ++r) {
                    int s = sbase + mi * 16 + quad * 4 + r;
                    outp[(size_t)s * P_ + ni * 16 + ln] = f2bf(acc[mi][ni][r]);
                }
    } else {
        short* outp = vTb + ((size_t)(b * H_ + h)) * P_ * S_;
#pragma unroll
        for (int mi = 0; mi < 2; ++mi)
#pragma unroll
            for (int ni = 0; ni < 4; ++ni) {
                int p = ni * 16 + ln;
                int s = sbase + mi * 16 + quad * 4;  // 4 consecutive s in regs
                ushort4 u;
                u.x = (unsigned short)f2bf(acc[mi][ni][0]);
                u.y = (unsigned short)f2bf(acc[mi][ni][1]);
                u.z = (unsigned short)f2bf(acc[mi][ni][2]);
                u.w = (unsigned short)f2bf(acc[mi][ni][3]);
                *(ushort4*)(outp + (size_t)p * S_ + s) = u;
            }
    }
}

// ---------------------------------------------------------------------------
// Stage 2: qv[b,h] = q_heads[h] @ v[b,h]; B-operand is vT (already Bt form).
// ---------------------------------------------------------------------------
__global__ __launch_bounds__(256) void qv_mfma(
    const short* __restrict__ qhb,
    const short* __restrict__ vTb,
    short* __restrict__ qvb)
{
    __shared__ short As[128][72];
    __shared__ short Bs[64][72];
    const int tid = threadIdx.x;
    const int w = tid >> 6, lane = tid & 63, quad = lane >> 4, ln = lane & 15;
    const int m0 = blockIdx.x * 128;
    const int bh = blockIdx.y;
    const int h = bh % H_;

    f32x4 acc[2][4] = {};
    mfma_gemm_128x64(qhb + (size_t)h * S_ * S_ + (size_t)m0 * S_, S_,
                     vTb + (size_t)bh * P_ * S_, S_, S_, As, Bs, acc);

    short* outp = qvb + (size_t)bh * S_ * P_;
#pragma unroll
    for (int mi = 0; mi < 2; ++mi)
#pragma unroll
        for (int ni = 0; ni < 4; ++ni)
#pragma unroll
            for (int r = 0; r < 4; ++r) {
                int s = m0 + w * 32 + mi * 16 + quad * 4 + r;
                outp[(size_t)s * P_ + ni * 16 + ln] = f2bf(acc[mi][ni][r]);
            }
}

// ---------------------------------------------------------------------------
// Stage 3: flash attention, latency-oriented restructure.
//
// Round-1 evidence: dur identical (104.9 -> 104.1 us) despite VALUBusy
// 24.6->11.4% and 9x fewer bank conflicts; FETCH_SIZE pinned at 83 MB
// (unique inputs = 36 MB) -> bound by the L2-miss stream. Two causes:
//  (a) the 16 q-blocks of one bh round-robin all 8 XCDs -> each XCD's
//      private L2 refetches that bh's K/V; concurrent working set per XCD
//      thrashes 4 MiB.
//  (b) only 3 waves/SIMD max residency -> miss latency not hidden.
// Fix:
//  (a) XCD-locality map: 1D grid, xcd = id&7, each XCD owns 12 whole bh
//      (16 q-blocks contiguous in dispatch). Reusable K/V per XCD = 3 MB
//      < 4 MiB L2.
//  (b) 4 waves/block: row-half x jt-parity. No-max softmax partials are
//      additive -> one-time LDS sum of (o,l) at the end. 6 waves/SIMD.
// ---------------------------------------------------------------------------
template<bool DIAG>
__device__ __forceinline__ void flash_tile(
    const short* __restrict__ Kj,   // K tile base: rows [0,64) x P_
    const short* __restrict__ Vj,   // Vt + jt*64 (row stride S_)
    const bf16x8 (&qf)[2][2], short (*Pw)[72],
    f32x4 (&o)[2][4], float (&l)[2][4],
    int rowbase, int quad, int ln)
{
    const float c2 = 0.03608439182435161f * 1.4426950408889634f; // scale*log2(e)

    // S strips (2 x 16x64) = Q strips @ K^T ; kf straight from global (L2)
    f32x4 s[2][4] = {};
#pragma unroll
    for (int kc = 0; kc < 2; ++kc)
#pragma unroll
        for (int ni = 0; ni < 4; ++ni) {
            bf16x8 kf = *(const bf16x8*)(Kj + (size_t)(ni * 16 + ln) * P_ + kc * 32 + quad * 8);
            s[0][ni] = __builtin_amdgcn_mfma_f32_16x16x32_bf16(qf[0][kc], kf, s[0][ni], 0, 0, 0);
            s[1][ni] = __builtin_amdgcn_mfma_f32_16x16x32_bf16(qf[1][kc], kf, s[1][ni], 0, 0, 0);
        }

    // p = exp2(c2*s) (no max-subtract); zero masked AFTER exp; defer l-reduce
#pragma unroll
    for (int u = 0; u < 2; ++u)
#pragma unroll
        for (int r = 0; r < 4; ++r) {
            const int row = u * 16 + quad * 4 + r;   // row within this wave's 32
            float p[4];
#pragma unroll
            for (int ni = 0; ni < 4; ++ni) {
                float v = __builtin_amdgcn_exp2f(c2 * s[u][ni][r]);
                if (DIAG && (ni * 16 + ln) > (rowbase + row)) v = 0.f;
                p[ni] = v;
                l[u][r] += v;
            }
#pragma unroll
            for (int ni = 0; ni < 4; ++ni)
                Pw[row][ni * 16 + ln] = f2bf_hw(p[ni]);
        }

    // O strips += P @ V ; P via wave-private LDS (same-wave DS is in-order),
    // vb straight from global (L2)
#pragma unroll
    for (int kc = 0; kc < 2; ++kc) {
        bf16x8 pa0 = *(const bf16x8*)&Pw[ln][kc * 32 + quad * 8];
        bf16x8 pa1 = *(const bf16x8*)&Pw[16 + ln][kc * 32 + quad * 8];
#pragma unroll
        for (int ni = 0; ni < 4; ++ni) {
            bf16x8 vb = *(const bf16x8*)(Vj + (size_t)(ni * 16 + ln) * S_ + kc * 32 + quad * 8);
            o[0][ni] = __builtin_amdgcn_mfma_f32_16x16x32_bf16(pa0, vb, o[0][ni], 0, 0, 0);
            o[1][ni] = __builtin_amdgcn_mfma_f32_16x16x32_bf16(pa1, vb, o[1][ni], 0, 0, 0);
        }
    }
}

__global__ __launch_bounds__(256, 4) void flash_mfma(
    const short* __restrict__ kb,
    const short* __restrict__ qvb,
    const short* __restrict__ vTb,
    short* __restrict__ attn2)
{
    // Ps (per-tile P relayout) and the one-time (o,l) reduction buffers are
    // disjoint in time -> union to keep LDS at 21.5 KB (6+ blocks/CU).
    __shared__ union SMem {
        short ps[4][32][72];
        struct { float ored[2][32][68]; float lred[2][64][8]; } red;
    } sm;

    const int tid = threadIdx.x;
    const int w = tid >> 6, lane = tid & 63, quad = lane >> 4, ln = lane & 15;
    const int rowhalf = w & 1, jpar = w >> 1;

    // XCD-locality map: xcd = id&7 (round-robin dispatch idiom); each XCD
    // gets 12 whole bh, q-blocks contiguous, long (high-qb) blocks first.
    const int lid = (int)blockIdx.x;
    const int xcd = lid & 7, slot = lid >> 3;       // slot in [0,192)
    const int bh  = xcd * 12 + (slot >> 4);
    const int qb  = 15 - (slot & 15);
    const int b = bh / H_, h = bh % H_;

    const short* Q  = kb  + (size_t)bh * S_ * P_ + ((size_t)qb * 64 + rowhalf * 32) * P_;
    const short* K  = qvb + (size_t)bh * S_ * P_;
    const short* Vt = vTb + (size_t)bh * P_ * S_;

    // Q fragments direct from global (one-time, coalesced)
    bf16x8 qf[2][2];
#pragma unroll
    for (int u = 0; u < 2; ++u)
#pragma unroll
        for (int kc = 0; kc < 2; ++kc)
            qf[u][kc] = *(const bf16x8*)(Q + (size_t)(u * 16 + ln) * P_ + kc * 32 + quad * 8);

    f32x4 o[2][4] = {};
    float l[2][4] = {};
    short (*Pw)[72] = sm.ps[w];

    // This wave handles tiles jt ≡ jpar (mod 2) in [0, qb]
    int jt = jpar;
    for (; jt < qb; jt += 2)
        flash_tile<false>(K + (size_t)jt * 64 * P_, Vt + jt * 64, qf, Pw, o, l,
                          rowhalf * 32, quad, ln);
    if (jt == qb)
        flash_tile<true>(K + (size_t)qb * 64 * P_, Vt + qb * 64, qf, Pw, o, l,
                         rowhalf * 32, quad, ln);

    // combine the two jt-parity waves per row-half (partials are additive)
    __syncthreads();                 // all Ps reads done before aliasing as red
    if (jpar == 1) {
#pragma unroll
        for (int u = 0; u < 2; ++u)
#pragma unroll
            for (int r = 0; r < 4; ++r)
                sm.red.lred[rowhalf][lane][u * 4 + r] = l[u][r];
#pragma unroll
        for (int u = 0; u < 2; ++u)
#pragma unroll
            for (int ni = 0; ni < 4; ++ni)
#pragma unroll
                for (int r = 0; r < 4; ++r)
                    sm.red.ored[rowhalf][u * 16 + quad * 4 + r][ni * 16 + ln] = o[u][ni][r];
    }
    __syncthreads();
    if (jpar == 0) {
#pragma unroll
        for (int u = 0; u < 2; ++u)
#pragma unroll
            for (int r = 0; r < 4; ++r)
                l[u][r] += sm.red.lred[rowhalf][lane][u * 4 + r];
#pragma unroll
        for (int u = 0; u < 2; ++u)
#pragma unroll
            for (int ni = 0; ni < 4; ++ni)
#pragma unroll
                for (int r = 0; r < 4; ++r)
                    o[u][ni][r] += sm.red.ored[rowhalf][u * 16 + quad * 4 + r][ni * 16 + ln];

        // epilogue: one row-sum reduce per row, then scale + store bf16
#pragma unroll
        for (int u = 0; u < 2; ++u)
#pragma unroll
            for (int r = 0; r < 4; ++r) {
                float lv = l[u][r];
#pragma unroll
                for (int off = 1; off < 16; off <<= 1)
                    lv += __shfl_xor(lv, off, 16);
                float inv = 1.0f / lv;
                int gi = qb * 64 + rowhalf * 32 + u * 16 + quad * 4 + r;
#pragma unroll
                for (int ni = 0; ni < 4; ++ni)
                    attn2[((size_t)b * S_ + gi) * (H_ * P_) + h * P_ + ni * 16 + ln] =
                        f2bf(o[u][ni][r] * inv);
            }
    }
}

// ---------------------------------------------------------------------------
// Stage 4: out(8192x768) = attn2 @ lifting, via liftT (Bt form). grid (64,12).
// ---------------------------------------------------------------------------
__global__ __launch_bounds__(256) void lift_mfma(
    const short* __restrict__ attn2,
    const short* __restrict__ liftT,
    float* __restrict__ outp)
{
    __shared__ short As[128][72];
    __shared__ short Bs[64][72];
    const int tid = threadIdx.x;
    const int w = tid >> 6, lane = tid & 63, quad = lane >> 4, ln = lane & 15;
    const int m0 = blockIdx.x * 128;
    const int n0 = blockIdx.y * 64;

    f32x4 acc[2][4] = {};
    mfma_gemm_128x64(attn2 + (size_t)m0 * E_, E_,
                     liftT + (size_t)n0 * E_, E_, E_, As, Bs, acc);

#pragma unroll
    for (int mi = 0; mi < 2; ++mi)
#pragma unroll
        for (int ni = 0; ni < 4; ++ni)
#pragma unroll
            for (int r = 0; r < 4; ++r) {
                int m = m0 + w * 32 + mi * 16 + quad * 4 + r;
                outp[(size_t)m * E_ + n0 + ni * 16 + ln] = acc[mi][ni][r];
            }
}

extern "C" void kernel_launch(void* const* d_in, const int* in_sizes, int n_in,
                              void* d_out, int out_size, void* d_ws, size_t ws_size,
                              hipStream_t stream) {
    (void)in_sizes; (void)n_in; (void)out_size; (void)ws_size;
    const float* x       = (const float*)d_in[0];
    const float* kproj   = (const float*)d_in[1];
    const float* vproj   = (const float*)d_in[2];
    const float* qheads  = (const float*)d_in[3];
    const float* lifting = (const float*)d_in[4];
    float* out = (float*)d_out;

    short* ws = (short*)d_ws;
    const size_t N_X   = (size_t)B_ * S_ * E_;          // 6,291,456
    const size_t N_QH  = (size_t)H_ * S_ * S_;          // 12,582,912
    const size_t N_W   = (size_t)H_ * P_ * E_;          //    589,824
    const size_t N_L   = (size_t)E_ * E_;               //    589,824
    const size_t N_KV  = (size_t)B_ * H_ * S_ * P_;     // 6,291,456

    short* xb    = ws;                 ws += N_X;
    short* qhb   = ws;                 ws += N_QH;
    short* kTw   = ws;                 ws += N_W;
    short* vTw   = ws;                 ws += N_W;
    short* liftT = ws;                 ws += N_L;
    short* kb    = ws;                 ws += N_KV;
    short* vTb   = ws;                 ws += N_KV;
    short* qvb   = ws;                 ws += N_KV;
    short* attn2 = ws;                 ws += N_KV;

    conv_bf16_kernel<<<(int)(N_X / 1024), 256, 0, stream>>>((const float4*)x, (ushort4*)xb);
    conv_bf16_kernel<<<(int)(N_QH / 1024), 256, 0, stream>>>((const float4*)qheads, (ushort4*)qhb);
    conv_T_kernel<<<dim3(E_ / 64, P_ / 64, H_), 256, 0, stream>>>(kproj, kTw, E_, P_);
    conv_T_kernel<<<dim3(E_ / 64, P_ / 64, H_), 256, 0, stream>>>(vproj, vTw, E_, P_);
    conv_T_kernel<<<dim3(E_ / 64, E_ / 64, 1), 256, 0, stream>>>(lifting, liftT, E_, E_);

    proj_kv_mfma<<<dim3((B_ * S_) / 128, H_, 2), 256, 0, stream>>>(xb, kTw, vTw, kb, vTb);
    qv_mfma<<<dim3(S_ / 128, B_ * H_), 256, 0, stream>>>(qhb, vTb, qvb);
    flash_mfma<<<dim3((S_ / 64) * B_ * H_), 256, 0, stream>>>(kb, qvb, vTb, attn2);
    lift_mfma<<<dim3((B_ * S_) / 128, E_ / 64), 256, 0, stream>>>(attn2, liftT, out);
}

// Round 3
// 299.438 us; speedup vs baseline: 1.2160x; 1.1411x over previous
//
#include <hip/hip_runtime.h>
#include <hip/hip_bf16.h>
#include <math.h>

#define B_ 8
#define S_ 1024
#define E_ 768
#define H_ 12
#define P_ 64

typedef __attribute__((ext_vector_type(8))) short bf16x8;
typedef __attribute__((ext_vector_type(4))) float f32x4;

__device__ __forceinline__ short f2bf(float f) {
    union { float f; unsigned u; } v; v.f = f;
    unsigned r = v.u + 0x7FFFu + ((v.u >> 16) & 1u);  // round-to-nearest-even
    return (short)(r >> 16);
}

// HW bf16 convert (compiler emits v_cvt path; m240: beats hand asm).
__device__ __forceinline__ short f2bf_hw(float f) {
    union { __hip_bfloat16 h; short s; } cv;
    cv.h = __float2bfloat16(f);
    return cv.s;
}

// ---------------------------------------------------------------------------
// fp32 -> bf16 straight conversion (n multiple of 1024)
// ---------------------------------------------------------------------------
__global__ __launch_bounds__(256) void conv_bf16_kernel(
    const float4* __restrict__ src, ushort4* __restrict__ dst)
{
    int idx = blockIdx.x * 256 + threadIdx.x;
    float4 f = src[idx];
    ushort4 u;
    u.x = (unsigned short)f2bf(f.x);
    u.y = (unsigned short)f2bf(f.y);
    u.z = (unsigned short)f2bf(f.z);
    u.w = (unsigned short)f2bf(f.w);
    dst[idx] = u;
}

// ---------------------------------------------------------------------------
// fp32 [batch][R][C] -> bf16 [batch][C][R] transpose. grid (R/64, C/64, batch)
// ---------------------------------------------------------------------------
__global__ __launch_bounds__(256) void conv_T_kernel(
    const float* __restrict__ src0, short* __restrict__ dst0, int R, int C)
{
    __shared__ short T[64][72];
    const int t = threadIdx.x;
    const int r0 = blockIdx.x * 64, c0 = blockIdx.y * 64;
    const size_t bo = (size_t)blockIdx.z * R * C;
    const float* src = src0 + bo;
    short* dst = dst0 + bo;
#pragma unroll
    for (int i = 0; i < 4; ++i) {
        int id = i * 256 + t;
        int r = id >> 4, c4 = id & 15;
        float4 f = *(const float4*)(src + (size_t)(r0 + r) * C + c0 + c4 * 4);
        T[c4 * 4 + 0][r] = f2bf(f.x);
        T[c4 * 4 + 1][r] = f2bf(f.y);
        T[c4 * 4 + 2][r] = f2bf(f.z);
        T[c4 * 4 + 3][r] = f2bf(f.w);
    }
    __syncthreads();
#pragma unroll
    for (int i = 0; i < 2; ++i) {
        int id = i * 256 + t;
        int cc = id >> 3, r8 = id & 7;
        *(uint4*)(dst + (size_t)(c0 + cc) * R + r0 + r8 * 8) = *(const uint4*)&T[cc][r8 * 8];
    }
}

// ---------------------------------------------------------------------------
// 8-wave MFMA GEMM core: C(128x128) = A(128xK) @ [B0;B1](128xK)^T.
// 512 threads = 8 waves: wm = w&3 (M strip of 32 rows), wn = w>>2 (N strip of
// 64 cols). B rows 0..63 from B0, 64..127 from B1 (lets callers stack two
// 64-row operands: k/v weights, batch pairs, column pairs).
// Fragment maps identical to the verified 128x64 core.
// ---------------------------------------------------------------------------
__device__ __forceinline__ void mfma_gemm_128x128(
    const short* __restrict__ A, int lda,
    const short* __restrict__ B0, const short* __restrict__ B1, int ldb, int K,
    short (*As)[72], short (*Bs)[72], f32x4 (&acc)[2][4])
{
    const int tid = threadIdx.x;
    const int w = tid >> 6, lane = tid & 63, quad = lane >> 4, ln = lane & 15;
    const int wm = w & 3, wn = w >> 2;

    // per-thread staging sources: row fixed across K-steps, col = k0 + c8*8
    const short* srcA[2]; short* dstA[2];
    const short* srcB[2]; short* dstB[2];
#pragma unroll
    for (int i = 0; i < 2; ++i) {
        int id = i * 512 + tid;
        int r = id >> 3, c8 = id & 7;
        srcA[i] = A + (size_t)r * lda + c8 * 8;
        dstA[i] = &As[r][c8 * 8];
        srcB[i] = (r < 64 ? B0 + (size_t)r * ldb : B1 + (size_t)(r - 64) * ldb) + c8 * 8;
        dstB[i] = &Bs[r][c8 * 8];
    }

    for (int k0 = 0; k0 < K; k0 += 64) {
        __syncthreads();
#pragma unroll
        for (int i = 0; i < 2; ++i)
            *(uint4*)dstA[i] = *(const uint4*)(srcA[i] + k0);
#pragma unroll
        for (int i = 0; i < 2; ++i)
            *(uint4*)dstB[i] = *(const uint4*)(srcB[i] + k0);
        __syncthreads();
#pragma unroll
        for (int kc = 0; kc < 2; ++kc) {
            bf16x8 a0 = *(const bf16x8*)&As[wm * 32 + ln][kc * 32 + quad * 8];
            bf16x8 a1 = *(const bf16x8*)&As[wm * 32 + 16 + ln][kc * 32 + quad * 8];
#pragma unroll
            for (int ni = 0; ni < 4; ++ni) {
                bf16x8 b = *(const bf16x8*)&Bs[wn * 64 + ni * 16 + ln][kc * 32 + quad * 8];
                acc[0][ni] = __builtin_amdgcn_mfma_f32_16x16x32_bf16(a0, b, acc[0][ni], 0, 0, 0);
                acc[1][ni] = __builtin_amdgcn_mfma_f32_16x16x32_bf16(a1, b, acc[1][ni], 0, 0, 0);
            }
        }
    }
}

// ---------------------------------------------------------------------------
// Stage 1: one block = (m-tile, head h); computes BOTH k (wn=0) and v (wn=1).
// A re-reads: 24 -> 12. 1D grid 768, XCD-chunked m-tiles (per-XCD A set
// 1.6 MB + weights 2.4 MB ~ L2-resident).
// ---------------------------------------------------------------------------
__global__ __launch_bounds__(512, 6) void proj_kv_mfma(
    const short* __restrict__ xb,
    const short* __restrict__ kTw,   // [h][p][e] bf16
    const short* __restrict__ vTw,
    short* __restrict__ kb,          // [b][h][s][p]
    short* __restrict__ vTb)         // [b][h][p][s]
{
    __shared__ short As[128][72];
    __shared__ short Bs[128][72];
    const int tid = threadIdx.x;
    const int w = tid >> 6, lane = tid & 63, quad = lane >> 4, ln = lane & 15;
    const int wm = w & 3, wn = w >> 2;

    const int lid = (int)blockIdx.x;          // 768 blocks
    const int xcd = lid & 7, s = lid >> 3;    // s in [0,96)
    const int mloc = s & 7, h = s >> 3;       // 8 m-tiles/xcd, 12 heads
    const int m0 = (xcd * 8 + mloc) * 128;

    f32x4 acc[2][4] = {};
    mfma_gemm_128x128(xb + (size_t)m0 * E_, E_,
                      kTw + (size_t)h * P_ * E_, vTw + (size_t)h * P_ * E_, E_, E_,
                      As, Bs, acc);

    const int b = m0 >> 10;
    const int sbase = (m0 & 1023) + wm * 32;
    if (wn == 0) {
        short* outp = kb + ((size_t)(b * H_ + h)) * S_ * P_;
#pragma unroll
        for (int mi = 0; mi < 2; ++mi)
#pragma unroll
            for (int ni = 0; ni < 4; ++ni)
#pragma unroll
                for (int r = 0; r < 4; ++r) {
                    int ss = sbase + mi * 16 + quad * 4 + r;
                    outp[(size_t)ss * P_ + ni * 16 + ln] = f2bf(acc[mi][ni][r]);
                }
    } else {
        short* outp = vTb + ((size_t)(b * H_ + h)) * P_ * S_;
#pragma unroll
        for (int mi = 0; mi < 2; ++mi)
#pragma unroll
            for (int ni = 0; ni < 4; ++ni) {
                int p = ni * 16 + ln;
                int ss = sbase + mi * 16 + quad * 4;  // 4 consecutive s in regs
                ushort4 u;
                u.x = (unsigned short)f2bf(acc[mi][ni][0]);
                u.y = (unsigned short)f2bf(acc[mi][ni][1]);
                u.z = (unsigned short)f2bf(acc[mi][ni][2]);
                u.w = (unsigned short)f2bf(acc[mi][ni][3]);
                *(ushort4*)(outp + (size_t)p * S_ + ss) = u;
            }
    }
}

// ---------------------------------------------------------------------------
// Stage 2: qv[b,h] = q_heads[h] @ v[b,h]; one block = (h, m-tile, b-pair),
// N=128 = [vT(b0,h); vT(b1,h)] -> A re-reads halve. XCD-contiguous h ranges
// keep each 2 MB q_heads panel in ~1 XCD's L2.
// ---------------------------------------------------------------------------
__global__ __launch_bounds__(512, 6) void qv_mfma(
    const short* __restrict__ qhb,
    const short* __restrict__ vTb,
    short* __restrict__ qvb)
{
    __shared__ short As[128][72];
    __shared__ short Bs[128][72];
    const int tid = threadIdx.x;
    const int w = tid >> 6, lane = tid & 63, quad = lane >> 4, ln = lane & 15;
    const int wm = w & 3, wn = w >> 2;

    const int lid = (int)blockIdx.x;             // 384 blocks
    const int xcd = lid & 7, s = lid >> 3;       // s in [0,48)
    const int virt = xcd * 48 + s;               // h-major, XCD-chunked
    const int h = virt >> 5;                     // 12 heads x 32 blocks
    const int rem = virt & 31;
    const int mt = rem >> 2, bp = rem & 3;       // 8 m-tiles, 4 b-pairs
    const int m0 = mt * 128;

    const short* Bv0 = vTb + (size_t)((bp * 2 + 0) * H_ + h) * P_ * S_;
    const short* Bv1 = vTb + (size_t)((bp * 2 + 1) * H_ + h) * P_ * S_;

    f32x4 acc[2][4] = {};
    mfma_gemm_128x128(qhb + (size_t)h * S_ * S_ + (size_t)m0 * S_, S_,
                      Bv0, Bv1, S_, S_, As, Bs, acc);

    const int b = bp * 2 + wn;
    short* outp = qvb + (size_t)(b * H_ + h) * S_ * P_;
#pragma unroll
    for (int mi = 0; mi < 2; ++mi)
#pragma unroll
        for (int ni = 0; ni < 4; ++ni)
#pragma unroll
            for (int r = 0; r < 4; ++r) {
                int ss = m0 + wm * 32 + mi * 16 + quad * 4 + r;
                outp[(size_t)ss * P_ + ni * 16 + ln] = f2bf(acc[mi][ni][r]);
            }
}

// ---------------------------------------------------------------------------
// Stage 3: flash attention (unchanged from round 2: XCD-local bh grouping,
// no-max softmax, barrier-free tiles, 4 waves = rowhalf x jt-parity).
// ---------------------------------------------------------------------------
template<bool DIAG>
__device__ __forceinline__ void flash_tile(
    const short* __restrict__ Kj,   // K tile base: rows [0,64) x P_
    const short* __restrict__ Vj,   // Vt + jt*64 (row stride S_)
    const bf16x8 (&qf)[2][2], short (*Pw)[72],
    f32x4 (&o)[2][4], float (&l)[2][4],
    int rowbase, int quad, int ln)
{
    const float c2 = 0.03608439182435161f * 1.4426950408889634f; // scale*log2(e)

    f32x4 s[2][4] = {};
#pragma unroll
    for (int kc = 0; kc < 2; ++kc)
#pragma unroll
        for (int ni = 0; ni < 4; ++ni) {
            bf16x8 kf = *(const bf16x8*)(Kj + (size_t)(ni * 16 + ln) * P_ + kc * 32 + quad * 8);
            s[0][ni] = __builtin_amdgcn_mfma_f32_16x16x32_bf16(qf[0][kc], kf, s[0][ni], 0, 0, 0);
            s[1][ni] = __builtin_amdgcn_mfma_f32_16x16x32_bf16(qf[1][kc], kf, s[1][ni], 0, 0, 0);
        }

#pragma unroll
    for (int u = 0; u < 2; ++u)
#pragma unroll
        for (int r = 0; r < 4; ++r) {
            const int row = u * 16 + quad * 4 + r;
            float p[4];
#pragma unroll
            for (int ni = 0; ni < 4; ++ni) {
                float v = __builtin_amdgcn_exp2f(c2 * s[u][ni][r]);
                if (DIAG && (ni * 16 + ln) > (rowbase + row)) v = 0.f;
                p[ni] = v;
                l[u][r] += v;
            }
#pragma unroll
            for (int ni = 0; ni < 4; ++ni)
                Pw[row][ni * 16 + ln] = f2bf_hw(p[ni]);
        }

#pragma unroll
    for (int kc = 0; kc < 2; ++kc) {
        bf16x8 pa0 = *(const bf16x8*)&Pw[ln][kc * 32 + quad * 8];
        bf16x8 pa1 = *(const bf16x8*)&Pw[16 + ln][kc * 32 + quad * 8];
#pragma unroll
        for (int ni = 0; ni < 4; ++ni) {
            bf16x8 vb = *(const bf16x8*)(Vj + (size_t)(ni * 16 + ln) * S_ + kc * 32 + quad * 8);
            o[0][ni] = __builtin_amdgcn_mfma_f32_16x16x32_bf16(pa0, vb, o[0][ni], 0, 0, 0);
            o[1][ni] = __builtin_amdgcn_mfma_f32_16x16x32_bf16(pa1, vb, o[1][ni], 0, 0, 0);
        }
    }
}

__global__ __launch_bounds__(256, 4) void flash_mfma(
    const short* __restrict__ kb,
    const short* __restrict__ qvb,
    const short* __restrict__ vTb,
    short* __restrict__ attn2)
{
    __shared__ union SMem {
        short ps[4][32][72];
        struct { float ored[2][32][68]; float lred[2][64][8]; } red;
    } sm;

    const int tid = threadIdx.x;
    const int w = tid >> 6, lane = tid & 63, quad = lane >> 4, ln = lane & 15;
    const int rowhalf = w & 1, jpar = w >> 1;

    const int lid = (int)blockIdx.x;
    const int xcd = lid & 7, slot = lid >> 3;       // slot in [0,192)
    const int bh  = xcd * 12 + (slot >> 4);
    const int qb  = 15 - (slot & 15);
    const int b = bh / H_, h = bh % H_;

    const short* Q  = kb  + (size_t)bh * S_ * P_ + ((size_t)qb * 64 + rowhalf * 32) * P_;
    const short* K  = qvb + (size_t)bh * S_ * P_;
    const short* Vt = vTb + (size_t)bh * P_ * S_;

    bf16x8 qf[2][2];
#pragma unroll
    for (int u = 0; u < 2; ++u)
#pragma unroll
        for (int kc = 0; kc < 2; ++kc)
            qf[u][kc] = *(const bf16x8*)(Q + (size_t)(u * 16 + ln) * P_ + kc * 32 + quad * 8);

    f32x4 o[2][4] = {};
    float l[2][4] = {};
    short (*Pw)[72] = sm.ps[w];

    int jt = jpar;
    for (; jt < qb; jt += 2)
        flash_tile<false>(K + (size_t)jt * 64 * P_, Vt + jt * 64, qf, Pw, o, l,
                          rowhalf * 32, quad, ln);
    if (jt == qb)
        flash_tile<true>(K + (size_t)qb * 64 * P_, Vt + qb * 64, qf, Pw, o, l,
                         rowhalf * 32, quad, ln);

    __syncthreads();
    if (jpar == 1) {
#pragma unroll
        for (int u = 0; u < 2; ++u)
#pragma unroll
            for (int r = 0; r < 4; ++r)
                sm.red.lred[rowhalf][lane][u * 4 + r] = l[u][r];
#pragma unroll
        for (int u = 0; u < 2; ++u)
#pragma unroll
            for (int ni = 0; ni < 4; ++ni)
#pragma unroll
                for (int r = 0; r < 4; ++r)
                    sm.red.ored[rowhalf][u * 16 + quad * 4 + r][ni * 16 + ln] = o[u][ni][r];
    }
    __syncthreads();
    if (jpar == 0) {
#pragma unroll
        for (int u = 0; u < 2; ++u)
#pragma unroll
            for (int r = 0; r < 4; ++r)
                l[u][r] += sm.red.lred[rowhalf][lane][u * 4 + r];
#pragma unroll
        for (int u = 0; u < 2; ++u)
#pragma unroll
            for (int ni = 0; ni < 4; ++ni)
#pragma unroll
                for (int r = 0; r < 4; ++r)
                    o[u][ni][r] += sm.red.ored[rowhalf][u * 16 + quad * 4 + r][ni * 16 + ln];

#pragma unroll
        for (int u = 0; u < 2; ++u)
#pragma unroll
            for (int r = 0; r < 4; ++r) {
                float lv = l[u][r];
#pragma unroll
                for (int off = 1; off < 16; off <<= 1)
                    lv += __shfl_xor(lv, off, 16);
                float inv = 1.0f / lv;
                int gi = qb * 64 + rowhalf * 32 + u * 16 + quad * 4 + r;
#pragma unroll
                for (int ni = 0; ni < 4; ++ni)
                    attn2[((size_t)b * S_ + gi) * (H_ * P_) + h * P_ + ni * 16 + ln] =
                        f2bf(o[u][ni][r] * inv);
            }
    }
}

// ---------------------------------------------------------------------------
// Stage 4: out = attn2 @ lifting; one block = (m-tile, n-pair), N=128 ->
// A re-reads 12 -> 6. XCD-chunked m-tiles.
// ---------------------------------------------------------------------------
__global__ __launch_bounds__(512, 6) void lift_mfma(
    const short* __restrict__ attn2,
    const short* __restrict__ liftT,
    float* __restrict__ outp)
{
    __shared__ short As[128][72];
    __shared__ short Bs[128][72];
    const int tid = threadIdx.x;
    const int w = tid >> 6, lane = tid & 63, quad = lane >> 4, ln = lane & 15;
    const int wm = w & 3, wn = w >> 2;

    const int lid = (int)blockIdx.x;             // 384 blocks
    const int xcd = lid & 7, s = lid >> 3;       // s in [0,48)
    const int mloc = s & 7, np = s >> 3;         // 8 m-tiles/xcd, 6 n-pairs
    const int m0 = (xcd * 8 + mloc) * 128;
    const int n0 = np * 128;

    f32x4 acc[2][4] = {};
    mfma_gemm_128x128(attn2 + (size_t)m0 * E_, E_,
                      liftT + (size_t)n0 * E_, liftT + (size_t)(n0 + 64) * E_, E_, E_,
                      As, Bs, acc);

#pragma unroll
    for (int mi = 0; mi < 2; ++mi)
#pragma unroll
        for (int ni = 0; ni < 4; ++ni)
#pragma unroll
            for (int r = 0; r < 4; ++r) {
                int m = m0 + wm * 32 + mi * 16 + quad * 4 + r;
                outp[(size_t)m * E_ + n0 + wn * 64 + ni * 16 + ln] = acc[mi][ni][r];
            }
}

extern "C" void kernel_launch(void* const* d_in, const int* in_sizes, int n_in,
                              void* d_out, int out_size, void* d_ws, size_t ws_size,
                              hipStream_t stream) {
    (void)in_sizes; (void)n_in; (void)out_size; (void)ws_size;
    const float* x       = (const float*)d_in[0];
    const float* kproj   = (const float*)d_in[1];
    const float* vproj   = (const float*)d_in[2];
    const float* qheads  = (const float*)d_in[3];
    const float* lifting = (const float*)d_in[4];
    float* out = (float*)d_out;

    short* ws = (short*)d_ws;
    const size_t N_X   = (size_t)B_ * S_ * E_;          // 6,291,456
    const size_t N_QH  = (size_t)H_ * S_ * S_;          // 12,582,912
    const size_t N_W   = (size_t)H_ * P_ * E_;          //    589,824
    const size_t N_L   = (size_t)E_ * E_;               //    589,824
    const size_t N_KV  = (size_t)B_ * H_ * S_ * P_;     // 6,291,456

    short* xb    = ws;                 ws += N_X;
    short* qhb   = ws;                 ws += N_QH;
    short* kTw   = ws;                 ws += N_W;
    short* vTw   = ws;                 ws += N_W;
    short* liftT = ws;                 ws += N_L;
    short* kb    = ws;                 ws += N_KV;
    short* vTb   = ws;                 ws += N_KV;
    short* qvb   = ws;                 ws += N_KV;
    short* attn2 = ws;                 ws += N_KV;

    conv_bf16_kernel<<<(int)(N_X / 1024), 256, 0, stream>>>((const float4*)x, (ushort4*)xb);
    conv_bf16_kernel<<<(int)(N_QH / 1024), 256, 0, stream>>>((const float4*)qheads, (ushort4*)qhb);
    conv_T_kernel<<<dim3(E_ / 64, P_ / 64, H_), 256, 0, stream>>>(kproj, kTw, E_, P_);
    conv_T_kernel<<<dim3(E_ / 64, P_ / 64, H_), 256, 0, stream>>>(vproj, vTw, E_, P_);
    conv_T_kernel<<<dim3(E_ / 64, E_ / 64, 1), 256, 0, stream>>>(lifting, liftT, E_, E_);

    proj_kv_mfma<<<dim3(768), 512, 0, stream>>>(xb, kTw, vTw, kb, vTb);
    qv_mfma<<<dim3(384), 512, 0, stream>>>(qhb, vTb, qvb);
    flash_mfma<<<dim3((S_ / 64) * B_ * H_), 256, 0, stream>>>(kb, qvb, vTb, attn2);
    lift_mfma<<<dim3(384), 512, 0, stream>>>(attn2, liftT, out);
}